// Round 1
// baseline (892.902 us; speedup 1.0000x reference)
//
#include <hip/hip_runtime.h>

// HyperDiffusion: two-phase hypergraph diffusion via on-the-fly CSR (counting sort),
// gather-based segment sums (no float atomics).
//
// C = 128 channels. Derivations on host:
//   N_V = in_sizes[0] / 128, NNZ = in_sizes[1], N_E = out_size/128 - N_V.

#define C_DIM 128

__global__ __launch_bounds__(256) void zero_int_kernel(int* __restrict__ p, int n) {
    int i = blockIdx.x * blockDim.x + threadIdx.x;
    if (i < n) p[i] = 0;
}

__global__ __launch_bounds__(256) void hist_kernel(const int* __restrict__ v_ids,
                                                   const int* __restrict__ e_ids,
                                                   int* __restrict__ deg_v,
                                                   int* __restrict__ deg_e, int nnz) {
    int k = blockIdx.x * blockDim.x + threadIdx.x;
    if (k < nnz) {
        atomicAdd(&deg_v[v_ids[k]], 1);
        atomicAdd(&deg_e[e_ids[k]], 1);
    }
}

// Single-block exclusive scan (chunked, 1024 threads x 4 elems/thread) that also
// emits inv_deg[i] = deg>0 ? 1/deg : 0.
__global__ __launch_bounds__(1024) void scan_kernel(const int* __restrict__ deg,
                                                    int* __restrict__ off,
                                                    float* __restrict__ inv_deg, int n) {
    __shared__ int wsum[16];
    __shared__ int s_carry;
    __shared__ int s_total;
    const int tid = threadIdx.x;
    const int lane = tid & 63;
    const int wid = tid >> 6;
    if (tid == 0) s_carry = 0;
    __syncthreads();
    for (int base = 0; base < n; base += 4096) {
        int idx = base + tid * 4;
        int v0 = 0, v1 = 0, v2 = 0, v3 = 0;
        if (idx + 3 < n) {
            v0 = deg[idx]; v1 = deg[idx + 1]; v2 = deg[idx + 2]; v3 = deg[idx + 3];
        } else {
            if (idx     < n) v0 = deg[idx];
            if (idx + 1 < n) v1 = deg[idx + 1];
            if (idx + 2 < n) v2 = deg[idx + 2];
            if (idx + 3 < n) v3 = deg[idx + 3];
        }
        int tsum = v0 + v1 + v2 + v3;
        // wave-inclusive scan of tsum
        int x = tsum;
        #pragma unroll
        for (int d = 1; d < 64; d <<= 1) {
            int y = __shfl_up(x, d, 64);
            if (lane >= d) x += y;
        }
        if (lane == 63) wsum[wid] = x;
        __syncthreads();
        if (tid == 0) {
            int run = 0;
            #pragma unroll
            for (int i = 0; i < 16; ++i) { int t = wsum[i]; wsum[i] = run; run += t; }
            s_total = run;
        }
        __syncthreads();
        int excl = s_carry + wsum[wid] + (x - tsum);
        if (idx < n)     { off[idx]     = excl;                inv_deg[idx]     = v0 > 0 ? 1.0f / (float)v0 : 0.0f; }
        if (idx + 1 < n) { off[idx + 1] = excl + v0;           inv_deg[idx + 1] = v1 > 0 ? 1.0f / (float)v1 : 0.0f; }
        if (idx + 2 < n) { off[idx + 2] = excl + v0 + v1;      inv_deg[idx + 2] = v2 > 0 ? 1.0f / (float)v2 : 0.0f; }
        if (idx + 3 < n) { off[idx + 3] = excl + v0 + v1 + v2; inv_deg[idx + 3] = v3 > 0 ? 1.0f / (float)v3 : 0.0f; }
        __syncthreads();
        if (tid == 0) s_carry += s_total;
        __syncthreads();
    }
    if (tid == 0) off[n] = s_carry;
}

// Counting-sort scatter: place each incidence's vertex id into its edge's CSR slot
// and each incidence's edge id into its vertex's CSR slot.
__global__ __launch_bounds__(256) void scatter_kernel(const int* __restrict__ v_ids,
                                                      const int* __restrict__ e_ids,
                                                      const int* __restrict__ off_v,
                                                      const int* __restrict__ off_e,
                                                      int* __restrict__ cur_v,
                                                      int* __restrict__ cur_e,
                                                      int* __restrict__ adj_v,  // edge ids grouped by vertex
                                                      int* __restrict__ adj_e,  // vertex ids grouped by edge
                                                      int nnz) {
    int k = blockIdx.x * blockDim.x + threadIdx.x;
    if (k < nnz) {
        int v = v_ids[k];
        int e = e_ids[k];
        int pe = off_e[e] + atomicAdd(&cur_e[e], 1);
        adj_e[pe] = v;
        int pv = off_v[v] + atomicAdd(&cur_v[v], 1);
        adj_v[pv] = e;
    }
}

// v2e: one wave per edge; lane owns 2 channels (float2). edge_feat[e] = sum_v X[v]*inv_deg_v[v]
__global__ __launch_bounds__(256) void v2e_kernel(const float* __restrict__ X,
                                                  const float* __restrict__ inv_deg_v,
                                                  const int* __restrict__ off_e,
                                                  const int* __restrict__ adj_e,
                                                  float* __restrict__ edge_feat, int n_e) {
    int e = blockIdx.x * 4 + (threadIdx.x >> 6);
    if (e >= n_e) return;
    int lane = threadIdx.x & 63;
    int beg = off_e[e], end = off_e[e + 1];
    float2 acc = make_float2(0.0f, 0.0f);
    for (int j = beg; j < end; ++j) {
        int v = adj_e[j];
        float w = inv_deg_v[v];
        const float2 xv = *reinterpret_cast<const float2*>(X + (size_t)v * C_DIM + lane * 2);
        acc.x += xv.x * w;
        acc.y += xv.y * w;
    }
    *reinterpret_cast<float2*>(edge_feat + (size_t)e * C_DIM + lane * 2) = acc;
}

// e2v: one wave per vertex; node_feat[v] = sum_e edge_feat[e]*inv_deg_e[e]
__global__ __launch_bounds__(256) void e2v_kernel(const float* __restrict__ edge_feat,
                                                  const float* __restrict__ inv_deg_e,
                                                  const int* __restrict__ off_v,
                                                  const int* __restrict__ adj_v,
                                                  float* __restrict__ node_feat, int n_v) {
    int v = blockIdx.x * 4 + (threadIdx.x >> 6);
    if (v >= n_v) return;
    int lane = threadIdx.x & 63;
    int beg = off_v[v], end = off_v[v + 1];
    float2 acc = make_float2(0.0f, 0.0f);
    for (int j = beg; j < end; ++j) {
        int e = adj_v[j];
        float w = inv_deg_e[e];
        const float2 ef = *reinterpret_cast<const float2*>(edge_feat + (size_t)e * C_DIM + lane * 2);
        acc.x += ef.x * w;
        acc.y += ef.y * w;
    }
    *reinterpret_cast<float2*>(node_feat + (size_t)v * C_DIM + lane * 2) = acc;
}

extern "C" void kernel_launch(void* const* d_in, const int* in_sizes, int n_in,
                              void* d_out, int out_size, void* d_ws, size_t ws_size,
                              hipStream_t stream) {
    const float* X    = (const float*)d_in[0];
    const int* v_ids  = (const int*)d_in[1];
    const int* e_ids  = (const int*)d_in[2];

    const int n_v  = in_sizes[0] / C_DIM;
    const int nnz  = in_sizes[1];
    const int n_e  = out_size / C_DIM - n_v;

    float* node_feat = (float*)d_out;                       // [n_v, 128]
    float* edge_feat = (float*)d_out + (size_t)n_v * C_DIM; // [n_e, 128]

    // Workspace layout (ints/floats, all 4B):
    int* ws = (int*)d_ws;
    int* deg_v = ws;                 // n_v
    int* deg_e = deg_v + n_v;        // n_e
    int* cur_v = deg_e + n_e;        // n_v
    int* cur_e = cur_v + n_v;        // n_e
    int* off_v = cur_e + n_e;        // n_v + 1
    int* off_e = off_v + n_v + 1;    // n_e + 1
    float* inv_deg_v = (float*)(off_e + n_e + 1); // n_v
    float* inv_deg_e = inv_deg_v + n_v;           // n_e
    int* adj_e = (int*)(inv_deg_e + n_e);         // nnz (vertex ids grouped by edge)
    int* adj_v = adj_e + nnz;                     // nnz (edge ids grouped by vertex)

    // 1. zero deg_v|deg_e|cur_v|cur_e (contiguous block of 2*(n_v+n_e) ints)
    {
        int nzero = 2 * (n_v + n_e);
        zero_int_kernel<<<(nzero + 255) / 256, 256, 0, stream>>>(deg_v, nzero);
    }
    // 2. degree histograms
    hist_kernel<<<(nnz + 255) / 256, 256, 0, stream>>>(v_ids, e_ids, deg_v, deg_e, nnz);
    // 3. exclusive scans + inverse degrees
    scan_kernel<<<1, 1024, 0, stream>>>(deg_e, off_e, inv_deg_e, n_e);
    scan_kernel<<<1, 1024, 0, stream>>>(deg_v, off_v, inv_deg_v, n_v);
    // 4. counting-sort scatter into CSR slots
    scatter_kernel<<<(nnz + 255) / 256, 256, 0, stream>>>(v_ids, e_ids, off_v, off_e,
                                                          cur_v, cur_e, adj_v, adj_e, nnz);
    // 5. v2e gather: edge_feat (unnormalized sum — this IS output #2)
    v2e_kernel<<<(n_e + 3) / 4, 256, 0, stream>>>(X, inv_deg_v, off_e, adj_e, edge_feat, n_e);
    // 6. e2v gather: node_feat (folds inv_deg_e on the fly)
    e2v_kernel<<<(n_v + 3) / 4, 256, 0, stream>>>(edge_feat, inv_deg_e, off_v, adj_v, node_feat, n_v);
}